// Round 10
// baseline (5634.193 us; speedup 1.0000x reference)
//
#include <hip/hip_runtime.h>
#include <hip/hip_bf16.h>

// Problem constants
#define BB 32
#define SS 512
#define DD 256
#define HH 256
#define GG 1024          // 4*H
#define MM (SS*BB)       // 16384 rows, m = s*32 + b
#define NSENT 16
#define TT 12
#define TAG_START 10
#define TAG_STOP 11

typedef unsigned long long u64;
typedef unsigned int u32;

__device__ __forceinline__ float sigm(float x) {
  x = fminf(fmaxf(x, -15.f), 15.f);
  return 1.f / (1.f + __expf(-x));
}
__device__ __forceinline__ float tanh_fast(float x) {
  x = fminf(fmaxf(x, -15.f), 15.f);
  float e = __expf(2.f * x);
  return (e - 1.f) / (e + 1.f);
}

// ---------------- embed gather: X1[m][d] = embed[inputs[b][s]][d], m = s*32+b
__global__ void embed_kernel(const int* __restrict__ toks, const float* __restrict__ emb,
                             float* __restrict__ X1) {
  int m = blockIdx.x;
  int s = m >> 5, b = m & 31;
  int tok = toks[b * SS + s];
  ((float4*)(X1 + (size_t)m * DD))[threadIdx.x] =
      ((const float4*)(emb + (size_t)tok * DD))[threadIdx.x];
}

// ---------------- fp32 NT GEMM: C[M,N] = A[M,K] @ W[N,K]^T + bias
// 128x128 tile, 8x8 per thread (4+4 row/col split so LDS strides are 2-way max).
// ld 132 pad; transposed staging writes consecutive-bank (2-way, free).
// Register double-buffer: chunk kk+16's global loads issue before the compute
// block so their latency hides under the 1024-FMA chunk.
__launch_bounds__(256)
__global__ void gemm_nt(const float* __restrict__ A, const float* __restrict__ W,
                        const float* __restrict__ bias, float* __restrict__ C,
                        int K, int ldC) {
  __shared__ float As[16 * 132];
  __shared__ float Ws[16 * 132];
  const int tid = threadIdx.x;
  const int n0 = blockIdx.x * 128, m0 = blockIdx.y * 128;
  const int row = tid & 127, half = tid >> 7;    // staging: 128 rows x 2 k-halves
  const int tx = tid & 15, ty = tid >> 4;        // compute: 16x16 thread grid
  const int kb = half * 8;
  float acc[8][8] = {};
  const float* Arow = A + (size_t)(m0 + row) * K;
  const float* Wrow = W + (size_t)(n0 + row) * K;
  float4 a0r = *(const float4*)(Arow + kb);
  float4 a1r = *(const float4*)(Arow + kb + 4);
  float4 w0r = *(const float4*)(Wrow + kb);
  float4 w1r = *(const float4*)(Wrow + kb + 4);
  for (int kk = 0; kk < K; kk += 16) {
    __syncthreads();   // prior compute done before LDS overwrite (no-op 1st iter)
    As[(kb + 0) * 132 + row] = a0r.x; As[(kb + 1) * 132 + row] = a0r.y;
    As[(kb + 2) * 132 + row] = a0r.z; As[(kb + 3) * 132 + row] = a0r.w;
    As[(kb + 4) * 132 + row] = a1r.x; As[(kb + 5) * 132 + row] = a1r.y;
    As[(kb + 6) * 132 + row] = a1r.z; As[(kb + 7) * 132 + row] = a1r.w;
    Ws[(kb + 0) * 132 + row] = w0r.x; Ws[(kb + 1) * 132 + row] = w0r.y;
    Ws[(kb + 2) * 132 + row] = w0r.z; Ws[(kb + 3) * 132 + row] = w0r.w;
    Ws[(kb + 4) * 132 + row] = w1r.x; Ws[(kb + 5) * 132 + row] = w1r.y;
    Ws[(kb + 6) * 132 + row] = w1r.z; Ws[(kb + 7) * 132 + row] = w1r.w;
    __syncthreads();
    if (kk + 16 < K) {
      a0r = *(const float4*)(Arow + kk + 16 + kb);
      a1r = *(const float4*)(Arow + kk + 16 + kb + 4);
      w0r = *(const float4*)(Wrow + kk + 16 + kb);
      w1r = *(const float4*)(Wrow + kk + 16 + kb + 4);
    }
#pragma unroll
    for (int kl = 0; kl < 16; ++kl) {
      const float4 alo = *(const float4*)&As[kl * 132 + ty * 4];
      const float4 ahi = *(const float4*)&As[kl * 132 + 64 + ty * 4];
      const float4 wlo = *(const float4*)&Ws[kl * 132 + tx * 4];
      const float4 whi = *(const float4*)&Ws[kl * 132 + 64 + tx * 4];
      const float am[8] = {alo.x, alo.y, alo.z, alo.w, ahi.x, ahi.y, ahi.z, ahi.w};
      const float wm[8] = {wlo.x, wlo.y, wlo.z, wlo.w, whi.x, whi.y, whi.z, whi.w};
#pragma unroll
      for (int i = 0; i < 8; ++i)
#pragma unroll
        for (int j = 0; j < 8; ++j) acc[i][j] = fmaf(am[i], wm[j], acc[i][j]);
    }
  }
  float4 blo = make_float4(0.f, 0.f, 0.f, 0.f), bhi = blo;
  if (bias) {
    blo = *(const float4*)(bias + n0 + tx * 4);
    bhi = *(const float4*)(bias + n0 + 64 + tx * 4);
  }
#pragma unroll
  for (int i = 0; i < 8; ++i) {
    const int m = m0 + ((i < 4) ? (ty * 4 + i) : (64 + ty * 4 + i - 4));
    float4 lo = make_float4(acc[i][0] + blo.x, acc[i][1] + blo.y,
                            acc[i][2] + blo.z, acc[i][3] + blo.w);
    float4 hi = make_float4(acc[i][4] + bhi.x, acc[i][5] + bhi.y,
                            acc[i][6] + bhi.z, acc[i][7] + bhi.w);
    *(float4*)(C + (size_t)m * ldC + n0 + tx * 4) = lo;
    *(float4*)(C + (size_t)m * ldC + n0 + 64 + tx * 4) = hi;
  }
}

// ---------------- whh repack: LANE-keyed layout + XOR swizzle (verified R9:
// SQ_LDS_BANK_CONFLICT = 0, absmax = 0).  Lane l reads
// whh_lds[l*256 + ((k4 ^ (l&63))*4 + ki)]; stored at position p4 is k-block
// p4^(l&63); contents are the row for the quad-epilogue mapping:
//   ln=l&63, wv=l>>6, q=ln&3, jl=wv*16+(ln>>2), g = q*256 + sl*32 + jl.
__global__ void prep_whh(const float* __restrict__ whh, float* __restrict__ out) {
  int idx = blockIdx.x * 256 + threadIdx.x;        // 2*8*128*256 = 524288
  int pos = idx & 255;
  int l = (idx >> 8) & 127;
  int sl = (idx >> 15) & 7;
  int dir = idx >> 18;
  int ki = pos & 3;
  int k4 = (pos >> 2) ^ (l & 63);
  int k = k4 * 4 + ki;
  int ln = l & 63, wv = l >> 6;
  int q = ln & 3, jl = wv * 16 + (ln >> 2);
  int g = q * 256 + sl * 32 + jl;
  out[idx] = whh[(size_t)(dir * GG + g) * HH + k];
}

// ---------------- LSTM recurrence (one layer, both dirs), one chain per wg.
// grid = 256: bid = (d + 2*bg) + 32*sl.  Sync: self-flagging tagged 8B words,
// relaxed agent-scope atomics, t-parity double buffer; per-thread barrier-free
// poll; ONE __syncthreads per step.  Epilogue: ALL 128 lanes compute their own
// gate's activation in parallel (1 transcendental each), shuffles carry
// ACTIVATED values, q==0 lane does cs = af*c + ai*ag; hn = ao*tanh(cs) — one
// tanh on the serial path.  hist is written PRODUCER-side by q==0 lanes after
// the tagged stores (ack overlaps the next spin; no store drains at the
// barrier ahead of it).
__launch_bounds__(128)
__global__ void rec_kernel(const float* __restrict__ Xp, const float* __restrict__ whh_p,
                           float* __restrict__ hist, u64* __restrict__ hx) {
  __shared__ float whh_lds[32768];   // [lane*256 + swz(k)], 128KB
  __shared__ float h_lds[1024];      // [par][c*256 + k]
  const int tid = threadIdx.x;
  const int bid = blockIdx.x;
  const int sl = bid >> 5;
  const int db = bid & 31;
  const int d = db & 1;
  const int bg = db >> 1;
  const int wv = tid >> 6, ln = tid & 63;
  const int q = ln & 3;                    // gate (i,f,g,o)
  const int jl = (wv << 4) + (ln >> 2);    // hidden unit j 0..31
  const int swz = tid & 63;                // LANE-keyed swizzle (matches prep)
  const float* wp = whh_p + (size_t)(d * 8 + sl) * 32768;
  for (int i = tid * 4; i < 32768; i += 512)
    *(float4*)&whh_lds[i] = *(const float4*)&wp[i];
  const float* XpD = Xp + (size_t)d * MM * GG;
  const int gcol = q * 256 + sl * 32 + jl;       // xp column for my gate row
  float creg0 = 0.f, creg1 = 0.f;                // cell state (valid in q==0 lanes)
  // group base: hx[slot][d][bg][512]
  u64* grp[2] = { hx + ((size_t)(0 * 2 + d) * 16 + bg) * 512,
                  hx + ((size_t)(1 * 2 + d) * 16 + bg) * 512 };
  __syncthreads();   // whh_lds ready
  for (int t = 0; t < SS; ++t) {
    const int s = d ? (SS - 1 - t) : t;
    // xp loads issued before the spin: HBM latency hides under it
    const int m0 = s * BB + bg * 2;
    const float xp0 = XpD[(size_t)m0 * GG + gcol];
    const float xp1 = XpD[(size_t)(m0 + 1) * GG + gcol];
    // ---- per-thread barrier-free spin on my 4 tagged words ----
    u64 w0, w1, w2, w3;
    {
      u64* base = grp[t & 1] + tid * 4;
      w0 = __hip_atomic_load(base + 0, __ATOMIC_RELAXED, __HIP_MEMORY_SCOPE_AGENT);
      w1 = __hip_atomic_load(base + 1, __ATOMIC_RELAXED, __HIP_MEMORY_SCOPE_AGENT);
      w2 = __hip_atomic_load(base + 2, __ATOMIC_RELAXED, __HIP_MEMORY_SCOPE_AGENT);
      w3 = __hip_atomic_load(base + 3, __ATOMIC_RELAXED, __HIP_MEMORY_SCOPE_AGENT);
      while (((u32)(w0 >> 32) != (u32)t) | ((u32)(w1 >> 32) != (u32)t) |
             ((u32)(w2 >> 32) != (u32)t) | ((u32)(w3 >> 32) != (u32)t)) {
        __builtin_amdgcn_s_sleep(1);
        w0 = __hip_atomic_load(base + 0, __ATOMIC_RELAXED, __HIP_MEMORY_SCOPE_AGENT);
        w1 = __hip_atomic_load(base + 1, __ATOMIC_RELAXED, __HIP_MEMORY_SCOPE_AGENT);
        w2 = __hip_atomic_load(base + 2, __ATOMIC_RELAXED, __HIP_MEMORY_SCOPE_AGENT);
        w3 = __hip_atomic_load(base + 3, __ATOMIC_RELAXED, __HIP_MEMORY_SCOPE_AGENT);
      }
    }
    float* hbuf = h_lds + (t & 1) * 512;
    *(float4*)&hbuf[tid * 4] = make_float4(
        __uint_as_float((u32)w0), __uint_as_float((u32)w1),
        __uint_as_float((u32)w2), __uint_as_float((u32)w3));
    __syncthreads();   // the step's ONLY barrier: h staging complete
    float acc0 = 0.f, acc1 = 0.f;
#pragma unroll 8
    for (int k4 = 0; k4 < 64; ++k4) {
      const float4 w = *(const float4*)&whh_lds[tid * 256 + ((k4 ^ swz) << 2)];
      const float4 h0 = *(const float4*)&hbuf[k4 * 4];           // broadcast (free)
      const float4 h1 = *(const float4*)&hbuf[256 + k4 * 4];
      acc0 = fmaf(w.x, h0.x, acc0); acc0 = fmaf(w.y, h0.y, acc0);
      acc0 = fmaf(w.z, h0.z, acc0); acc0 = fmaf(w.w, h0.w, acc0);
      acc1 = fmaf(w.x, h1.x, acc1); acc1 = fmaf(w.y, h1.y, acc1);
      acc1 = fmaf(w.z, h1.z, acc1); acc1 = fmaf(w.w, h1.w, acc1);
    }
    const float gv0 = acc0 + xp0, gv1 = acc1 + xp1;   // my gate's preactivation
    // PRE-ACTIVATION: every lane activates its own gate in parallel
    const float a0 = (q == 2) ? tanh_fast(gv0) : sigm(gv0);
    const float a1 = (q == 2) ? tanh_fast(gv1) : sigm(gv1);
    // quad shuffle of ACTIVATED values: q==0 gathers f(q1), g(q2), o(q3)
    const float af0 = __shfl_xor(a0, 1), af1 = __shfl_xor(a1, 1);
    const float ag0 = __shfl_xor(a0, 2), ag1 = __shfl_xor(a1, 2);
    const float ao0 = __shfl_xor(a0, 3), ao1 = __shfl_xor(a1, 3);
    if (q == 0) {
      const float cs0 = af0 * creg0 + a0 * ag0;     // a0 = sigm(i)
      creg0 = cs0;
      const float hn0 = ao0 * tanh_fast(cs0);
      const float cs1 = af1 * creg1 + a1 * ag1;
      creg1 = cs1;
      const float hn1 = ao1 * tanh_fast(cs1);
      u64* dst = grp[(t + 1) & 1] + sl * 32 + jl;
      __hip_atomic_store(dst, ((u64)(u32)(t + 1) << 32) | (u64)__float_as_uint(hn0),
                         __ATOMIC_RELAXED, __HIP_MEMORY_SCOPE_AGENT);
      __hip_atomic_store(dst + 256, ((u64)(u32)(t + 1) << 32) | (u64)__float_as_uint(hn1),
                         __ATOMIC_RELAXED, __HIP_MEMORY_SCOPE_AGENT);
      // producer-side hist (own slice); issued after hx stores, ack overlaps spin
      hist[(size_t)(s * BB + bg * 2 + 0) * 512 + d * 256 + sl * 32 + jl] = hn0;
      hist[(size_t)(s * BB + bg * 2 + 1) * 512 + d * 256 + sl * 32 + jl] = hn1;
    }
  }
}

// ---------------- attention: scores over NS=16 sentence embs, softmax, g; writes comb[512:1024]
__global__ void att_kernel(float* __restrict__ comb, const float* __restrict__ sent) {
  __shared__ float sl[NSENT * 512];   // 32 KB
  __shared__ float wxr[512];
  __shared__ float parts[256];
  __shared__ float aw[NSENT];
  __shared__ float red0;
  const int tid = threadIdx.x;
  const int b = blockIdx.y;
  const int s0 = blockIdx.x * 32;
  for (int i = tid; i < NSENT * 512; i += 256) sl[i] = sent[(size_t)b * NSENT * 512 + i];
  __syncthreads();
  for (int si = 0; si < 32; ++si) {
    const int m = (s0 + si) * BB + b;
    float* crow = comb + (size_t)m * 1024;
    for (int i = tid; i < 512; i += 256) wxr[i] = crow[i];
    __syncthreads();
    const int n = tid >> 4, kp = tid & 15;
    float p = 0.f;
#pragma unroll 8
    for (int f = kp * 32; f < kp * 32 + 32; ++f) p = fmaf(wxr[f], sl[n * 512 + f], p);
    parts[tid] = p;
    __syncthreads();
    if (tid < NSENT) {
      float sc = 0.f;
      for (int qq = 0; qq < 16; ++qq) sc += parts[tid * 16 + qq];
      aw[tid] = sc;
    }
    __syncthreads();
    if (tid == 0) {
      float mx = aw[0];
      for (int qq = 1; qq < NSENT; ++qq) mx = fmaxf(mx, aw[qq]);
      float sm = 0.f;
      for (int qq = 0; qq < NSENT; ++qq) { float e = expf(aw[qq] - mx); aw[qq] = e; sm += e; }
      red0 = 1.f / sm;
    }
    __syncthreads();
    const float inv = red0;
    for (int f = tid; f < 512; f += 256) {
      float g = 0.f;
#pragma unroll
      for (int qq = 0; qq < NSENT; ++qq) g = fmaf(aw[qq], sl[qq * 512 + f], g);
      crow[512 + f] = g * inv;
    }
    __syncthreads();
  }
}

// ---------------- feats[m][t] = l2m[m][:] . h2t_w[t][:] + h2t_b[t]; wave per row
__global__ void feats_kernel(const float* __restrict__ l2m, const float* __restrict__ w,
                             const float* __restrict__ bias, float* __restrict__ feats) {
  const int wave = threadIdx.x >> 6, lane = threadIdx.x & 63;
  const int m = blockIdx.x * 4 + wave;
  const float* row = l2m + (size_t)m * 512;
  float rv[8];
#pragma unroll
  for (int i = 0; i < 8; ++i) rv[i] = row[lane + i * 64];
  for (int t = 0; t < TT; ++t) {
    const float* wr = w + t * 512;
    float p = 0.f;
#pragma unroll
    for (int i = 0; i < 8; ++i) p = fmaf(rv[i], wr[lane + i * 64], p);
#pragma unroll
    for (int off = 32; off; off >>= 1) p += __shfl_down(p, off);
    if (lane == 0) feats[(size_t)m * TT + t] = p + bias[t];
  }
}

// ---------------- viterbi per batch; 1 wave, whole DP in LDS
__global__ void viterbi_kernel(const float* __restrict__ feats, const float* __restrict__ trans,
                               int* __restrict__ out) {
  __shared__ float flds[SS * TT];
  __shared__ unsigned char bp[SS * TT];
  __shared__ float tr[TT * TT];
  __shared__ float fv[TT];
  __shared__ float tv[TT];
  __shared__ int pathS[SS];
  const int b = blockIdx.x, tid = threadIdx.x;
  for (int i = tid; i < SS * TT; i += 64) {
    int s = i / TT, t = i - s * TT;
    flds[i] = feats[(size_t)(s * BB + b) * TT + t];
  }
  for (int i = tid; i < TT * TT; i += 64) tr[i] = trans[i];
  if (tid < TT) fv[tid] = (tid == TAG_START) ? 0.f : -10000.f;
  __syncthreads();
  for (int s = 0; s < SS; ++s) {
    float nf = 0.f;
    if (tid < TT) {
      float mx = -1e30f;
      int bj = 0;
#pragma unroll
      for (int jj = 0; jj < TT; ++jj) {
        float v = fv[jj] + tr[tid * TT + jj];
        if (v > mx) { mx = v; bj = jj; }
      }
      nf = mx + flds[s * TT + tid];
      bp[s * TT + tid] = (unsigned char)bj;
    }
    __syncthreads();
    if (tid < TT) fv[tid] = nf;
    __syncthreads();
  }
  if (tid < TT) tv[tid] = fv[tid] + tr[TAG_STOP * TT + tid];
  __syncthreads();
  if (tid == 0) {
    int best = 0;
    float mx = tv[0];
    for (int jj = 1; jj < TT; ++jj)
      if (tv[jj] > mx) { mx = tv[jj]; best = jj; }
    pathS[SS - 1] = best;
    for (int s = SS - 1; s > 0; --s) { best = bp[s * TT + best]; pathS[s - 1] = best; }
  }
  __syncthreads();
  for (int s = tid; s < SS; s += 64) out[b * SS + s] = pathS[s];
}

// ---------------- workspace layout (bytes) — total ~240.4 MB < 256 MB ----------------
#define OFF_XP    ((size_t)0)               // 2*16384*1024*4 = 134217728
#define OFF_COMB  ((size_t)134217728)       // 16384*1024*4 = 67108864 (X1 and l2m alias here)
#define OFF_WORD  ((size_t)201326592)       // 16384*512*4  = 33554432
#define OFF_WT1   ((size_t)234881024)       // 2097152
#define OFF_WT2   ((size_t)236978176)       // 2097152
#define OFF_FEATS ((size_t)239075328)       // 786432
#define OFF_HX1   ((size_t)239861760)       // 262144  (2 slots * 2 dir * 16 g * 512 u64)
#define OFF_HX2   ((size_t)240123904)       // 262144

extern "C" void kernel_launch(void* const* d_in, const int* in_sizes, int n_in,
                              void* d_out, int out_size, void* d_ws, size_t ws_size,
                              hipStream_t stream) {
  const int* inputs  = (const int*)d_in[0];
  const float* sent  = (const float*)d_in[1];
  const float* emb   = (const float*)d_in[2];
  const float* l1wih = (const float*)d_in[3];
  const float* l1whh = (const float*)d_in[4];
  const float* l1b   = (const float*)d_in[5];
  const float* l2wih = (const float*)d_in[6];
  const float* l2whh = (const float*)d_in[7];
  const float* l2b   = (const float*)d_in[8];
  const float* attW  = (const float*)d_in[9];
  const float* h2tw  = (const float*)d_in[10];
  const float* h2tb  = (const float*)d_in[11];
  const float* trans = (const float*)d_in[12];
  int* out = (int*)d_out;
  char* ws = (char*)d_ws;

  float* Xp    = (float*)(ws + OFF_XP);
  float* comb  = (float*)(ws + OFF_COMB);
  float* word  = (float*)(ws + OFF_WORD);
  float* X1    = comb;   // X1 dead before comb is written (wx GEMM reads word only)
  float* l2m   = comb;   // comb dead before rec2 writes l2m
  float* wt1   = (float*)(ws + OFF_WT1);
  float* wt2   = (float*)(ws + OFF_WT2);
  float* feats = (float*)(ws + OFF_FEATS);
  u64* hx1     = (u64*)(ws + OFF_HX1);
  u64* hx2     = (u64*)(ws + OFF_HX2);

  // zero both tagged-h buffers (contiguous 512 KB): tag 0 == "h_{-1}=0 ready"
  hipMemsetAsync(ws + OFF_HX1, 0, 262144 * 2, stream);

  prep_whh<<<2048, 256, 0, stream>>>(l1whh, wt1);
  prep_whh<<<2048, 256, 0, stream>>>(l2whh, wt2);
  embed_kernel<<<MM, 64, 0, stream>>>(inputs, emb, X1);
  for (int d = 0; d < 2; ++d)
    gemm_nt<<<dim3(8, 128), 256, 0, stream>>>(X1, l1wih + (size_t)d * GG * DD,
                                              l1b + d * GG, Xp + (size_t)d * MM * GG,
                                              DD, GG);
  rec_kernel<<<256, 128, 0, stream>>>(Xp, wt1, word, hx1);
  gemm_nt<<<dim3(4, 128), 256, 0, stream>>>(word, attW, nullptr, comb, 512, 1024);
  att_kernel<<<dim3(16, 32), 256, 0, stream>>>(comb, sent);
  for (int d = 0; d < 2; ++d)
    gemm_nt<<<dim3(8, 128), 256, 0, stream>>>(comb, l2wih + (size_t)d * GG * GG,
                                              l2b + d * GG, Xp + (size_t)d * MM * GG,
                                              GG, GG);
  rec_kernel<<<256, 128, 0, stream>>>(Xp, wt2, l2m, hx2);
  feats_kernel<<<MM / 4, 256, 0, stream>>>(l2m, h2tw, h2tb, feats);
  viterbi_kernel<<<BB, 64, 0, stream>>>(feats, trans, out);
}

// Round 11
// 5064.429 us; speedup vs baseline: 1.1125x; 1.1125x over previous
//
#include <hip/hip_runtime.h>
#include <hip/hip_bf16.h>

// Problem constants
#define BB 32
#define SS 512
#define DD 256
#define HH 256
#define GG 1024          // 4*H
#define MM (SS*BB)       // 16384 rows, m = s*32 + b
#define NSENT 16
#define TT 12
#define TAG_START 10
#define TAG_STOP 11

typedef unsigned long long u64;
typedef unsigned int u32;

__device__ __forceinline__ float sigm(float x) {
  x = fminf(fmaxf(x, -15.f), 15.f);
  return 1.f / (1.f + __expf(-x));
}
__device__ __forceinline__ float tanh_fast(float x) {
  x = fminf(fmaxf(x, -15.f), 15.f);
  float e = __expf(2.f * x);
  return (e - 1.f) / (e + 1.f);
}

// ---------------- embed gather: X1[m][d] = embed[inputs[b][s]][d], m = s*32+b
__global__ void embed_kernel(const int* __restrict__ toks, const float* __restrict__ emb,
                             float* __restrict__ X1) {
  int m = blockIdx.x;
  int s = m >> 5, b = m & 31;
  int tok = toks[b * SS + s];
  ((float4*)(X1 + (size_t)m * DD))[threadIdx.x] =
      ((const float4*)(emb + (size_t)tok * DD))[threadIdx.x];
}

// ---------------- fp32 NT GEMM (R9-verified): C[M,N] = A[M,K] @ W[N,K]^T + bias
// 128x128 tile, 8x8 per thread (4+4 row/col split so LDS strides are 2-way max).
// ld 132 pad; transposed staging writes consecutive-bank (2-way, free).
__launch_bounds__(256)
__global__ void gemm_nt(const float* __restrict__ A, const float* __restrict__ W,
                        const float* __restrict__ bias, float* __restrict__ C,
                        int K, int ldC) {
  __shared__ float As[16 * 132];
  __shared__ float Ws[16 * 132];
  const int tid = threadIdx.x;
  const int n0 = blockIdx.x * 128, m0 = blockIdx.y * 128;
  const int row = tid & 127, half = tid >> 7;    // staging: 128 rows x 2 k-halves
  const int tx = tid & 15, ty = tid >> 4;        // compute: 16x16 thread grid
  float acc[8][8] = {};
  const float* Arow = A + (size_t)(m0 + row) * K;
  const float* Wrow = W + (size_t)(n0 + row) * K;
  for (int kk = 0; kk < K; kk += 16) {
    const int kb = half * 8;
    float4 a0 = *(const float4*)(Arow + kk + kb);
    float4 a1 = *(const float4*)(Arow + kk + kb + 4);
    float4 w0 = *(const float4*)(Wrow + kk + kb);
    float4 w1 = *(const float4*)(Wrow + kk + kb + 4);
    As[(kb + 0) * 132 + row] = a0.x; As[(kb + 1) * 132 + row] = a0.y;
    As[(kb + 2) * 132 + row] = a0.z; As[(kb + 3) * 132 + row] = a0.w;
    As[(kb + 4) * 132 + row] = a1.x; As[(kb + 5) * 132 + row] = a1.y;
    As[(kb + 6) * 132 + row] = a1.z; As[(kb + 7) * 132 + row] = a1.w;
    Ws[(kb + 0) * 132 + row] = w0.x; Ws[(kb + 1) * 132 + row] = w0.y;
    Ws[(kb + 2) * 132 + row] = w0.z; Ws[(kb + 3) * 132 + row] = w0.w;
    Ws[(kb + 4) * 132 + row] = w1.x; Ws[(kb + 5) * 132 + row] = w1.y;
    Ws[(kb + 6) * 132 + row] = w1.z; Ws[(kb + 7) * 132 + row] = w1.w;
    __syncthreads();
#pragma unroll
    for (int kl = 0; kl < 16; ++kl) {
      const float4 alo = *(const float4*)&As[kl * 132 + ty * 4];
      const float4 ahi = *(const float4*)&As[kl * 132 + 64 + ty * 4];
      const float4 wlo = *(const float4*)&Ws[kl * 132 + tx * 4];
      const float4 whi = *(const float4*)&Ws[kl * 132 + 64 + tx * 4];
      const float am[8] = {alo.x, alo.y, alo.z, alo.w, ahi.x, ahi.y, ahi.z, ahi.w};
      const float wm[8] = {wlo.x, wlo.y, wlo.z, wlo.w, whi.x, whi.y, whi.z, whi.w};
#pragma unroll
      for (int i = 0; i < 8; ++i)
#pragma unroll
        for (int j = 0; j < 8; ++j) acc[i][j] = fmaf(am[i], wm[j], acc[i][j]);
    }
    __syncthreads();
  }
  float4 blo = make_float4(0.f, 0.f, 0.f, 0.f), bhi = blo;
  if (bias) {
    blo = *(const float4*)(bias + n0 + tx * 4);
    bhi = *(const float4*)(bias + n0 + 64 + tx * 4);
  }
#pragma unroll
  for (int i = 0; i < 8; ++i) {
    const int m = m0 + ((i < 4) ? (ty * 4 + i) : (64 + ty * 4 + i - 4));
    float4 lo = make_float4(acc[i][0] + blo.x, acc[i][1] + blo.y,
                            acc[i][2] + blo.z, acc[i][3] + blo.w);
    float4 hi = make_float4(acc[i][4] + bhi.x, acc[i][5] + bhi.y,
                            acc[i][6] + bhi.z, acc[i][7] + bhi.w);
    *(float4*)(C + (size_t)m * ldC + n0 + tx * 4) = lo;
    *(float4*)(C + (size_t)m * ldC + n0 + 64 + tx * 4) = hi;
  }
}

// ---------------- whh repack (R6-verified): XOR-swizzle for conflict-free b128 reads.
// out[((dir*8+sl)*128 + r)*256 + ((k4 ^ (r&63))*4 + ki)] = whh[dir][g][k]
//   r = gate*32 + j, g = gate*256 + sl*32 + j, k = k4*4 + ki
__global__ void prep_whh(const float* __restrict__ whh, float* __restrict__ out) {
  int idx = blockIdx.x * 256 + threadIdx.x;        // 2*8*128*256 = 524288
  int pos = idx & 255;
  int r = (idx >> 8) & 127;
  int sl = (idx >> 15) & 7;
  int dir = idx >> 18;
  int ki = pos & 3;
  int k4 = (pos >> 2) ^ (r & 63);
  int k = k4 * 4 + ki;
  int g = (r >> 5) * 256 + sl * 32 + (r & 31);
  out[idx] = whh[(size_t)(dir * GG + g) * HH + k];
}

// ---------------- LSTM recurrence (R6-verified: 1920us/dispatch), one chain per wg.
// grid = 256: bid = (d + 2*bg) + 32*sl.  wg: slice sl (32 units), dir d, batches
// {2bg, 2bg+1}.  Sync: self-flagging 64-bit words (tag<<32 | float bits), relaxed
// agent-scope 8B atomics, double-buffered by t-parity.  Per-thread barrier-free
// poll; 2 barriers/step; LDS g_lds epilogue with 64 parallel lanes; consumer-side
// hist writes by the sl==0 wg from polled registers.
__launch_bounds__(128)
__global__ void rec_kernel(const float* __restrict__ Xp, const float* __restrict__ whh_p,
                           float* __restrict__ hist, u64* __restrict__ hx) {
  __shared__ float whh_lds[32768];   // [r*256 + swz(k)], 128KB
  __shared__ float h_lds[512];       // [c*256 + k]
  __shared__ float g_lds[256];       // [r*2 + c]
  const int tid = threadIdx.x;
  const int bid = blockIdx.x;
  const int sl = bid >> 5;
  const int db = bid & 31;
  const int d = db & 1;
  const int bg = db >> 1;
  const int r = tid;                 // gate row 0..127 (gate*32+j)
  const int swz = r & 63;
  const float* wp = whh_p + (size_t)(d * 8 + sl) * 32768;
  for (int i = tid * 4; i < 32768; i += 512)
    *(float4*)&whh_lds[i] = *(const float4*)&wp[i];
  const float* XpD = Xp + (size_t)d * MM * GG;
  const int gcol = (r >> 5) * 256 + sl * 32 + (r & 31);
  const int jj = tid & 31, cc = tid >> 5;        // producer epilogue mapping (tid<64)
  const int hc = tid >> 6, hk = (tid & 63) * 4;  // consumer word mapping: c*256+k = tid*4
  float creg = 0.f;                              // LSTM cell state (valid tid<64)
  // group base: hx[slot][d][bg][512]
  u64* grp[2] = { hx + ((size_t)(0 * 2 + d) * 16 + bg) * 512,
                  hx + ((size_t)(1 * 2 + d) * 16 + bg) * 512 };
  __syncthreads();   // whh_lds ready
  for (int t = 0; t < SS; ++t) {
    const int s = d ? (SS - 1 - t) : t;
    // xp loads issued before the spin: HBM latency hides under it
    const int m0 = s * BB + bg * 2;
    const float xp0 = XpD[(size_t)m0 * GG + gcol];
    const float xp1 = XpD[(size_t)(m0 + 1) * GG + gcol];
    // ---- per-thread barrier-free spin on my 4 tagged words ----
    u64 w0, w1, w2, w3;
    {
      u64* base = grp[t & 1] + tid * 4;
      w0 = __hip_atomic_load(base + 0, __ATOMIC_RELAXED, __HIP_MEMORY_SCOPE_AGENT);
      w1 = __hip_atomic_load(base + 1, __ATOMIC_RELAXED, __HIP_MEMORY_SCOPE_AGENT);
      w2 = __hip_atomic_load(base + 2, __ATOMIC_RELAXED, __HIP_MEMORY_SCOPE_AGENT);
      w3 = __hip_atomic_load(base + 3, __ATOMIC_RELAXED, __HIP_MEMORY_SCOPE_AGENT);
      while (((u32)(w0 >> 32) != (u32)t) | ((u32)(w1 >> 32) != (u32)t) |
             ((u32)(w2 >> 32) != (u32)t) | ((u32)(w3 >> 32) != (u32)t)) {
        __builtin_amdgcn_s_sleep(1);
        w0 = __hip_atomic_load(base + 0, __ATOMIC_RELAXED, __HIP_MEMORY_SCOPE_AGENT);
        w1 = __hip_atomic_load(base + 1, __ATOMIC_RELAXED, __HIP_MEMORY_SCOPE_AGENT);
        w2 = __hip_atomic_load(base + 2, __ATOMIC_RELAXED, __HIP_MEMORY_SCOPE_AGENT);
        w3 = __hip_atomic_load(base + 3, __ATOMIC_RELAXED, __HIP_MEMORY_SCOPE_AGENT);
      }
    }
    *(float4*)&h_lds[tid * 4] = make_float4(
        __uint_as_float((u32)w0), __uint_as_float((u32)w1),
        __uint_as_float((u32)w2), __uint_as_float((u32)w3));
    // consumer-side hist write for step t-1 (polled words = h_{t-1})
    if (sl == 0 && t > 0) {
      const int sp = d ? (SS - t) : (t - 1);
      *(float4*)&hist[(size_t)(sp * BB + bg * 2 + hc) * 512 + d * 256 + hk] =
          make_float4(__uint_as_float((u32)w0), __uint_as_float((u32)w1),
                      __uint_as_float((u32)w2), __uint_as_float((u32)w3));
    }
    __syncthreads();   // (b) h_lds complete
    {
      float acc0 = 0.f, acc1 = 0.f;
#pragma unroll 8
      for (int k4 = 0; k4 < 64; ++k4) {
        const float4 w = *(const float4*)&whh_lds[r * 256 + ((k4 ^ swz) << 2)];
        const float4 h0 = *(const float4*)&h_lds[k4 * 4];
        const float4 h1 = *(const float4*)&h_lds[256 + k4 * 4];
        acc0 = fmaf(w.x, h0.x, acc0); acc0 = fmaf(w.y, h0.y, acc0);
        acc0 = fmaf(w.z, h0.z, acc0); acc0 = fmaf(w.w, h0.w, acc0);
        acc1 = fmaf(w.x, h1.x, acc1); acc1 = fmaf(w.y, h1.y, acc1);
        acc1 = fmaf(w.z, h1.z, acc1); acc1 = fmaf(w.w, h1.w, acc1);
      }
      *(float2*)&g_lds[r * 2] = make_float2(acc0 + xp0, acc1 + xp1);
    }
    __syncthreads();   // (c) g_lds ready; also fences h_lds reads vs next-step writes
    if (tid < 64) {    // producer epilogue: single 8B L3 atomic on the critical path
      const float iv = g_lds[(jj) * 2 + cc];
      const float fv = g_lds[(32 + jj) * 2 + cc];
      const float gv = g_lds[(64 + jj) * 2 + cc];
      const float ov = g_lds[(96 + jj) * 2 + cc];
      const float cs = sigm(fv) * creg + sigm(iv) * tanh_fast(gv);
      creg = cs;
      const float hn = sigm(ov) * tanh_fast(cs);
      u64 w = ((u64)(u32)(t + 1) << 32) | (u64)__float_as_uint(hn);
      __hip_atomic_store(grp[(t + 1) & 1] + cc * 256 + sl * 32 + jj, w,
                         __ATOMIC_RELAXED, __HIP_MEMORY_SCOPE_AGENT);
    }
  }
  // flush the final h (tag SS, produced at end of t=SS-1) to hist — sl==0 wgs only
  if (sl == 0) {
    u64* base = grp[SS & 1] + tid * 4;
    u64 w0, w1, w2, w3;
    do {
      w0 = __hip_atomic_load(base + 0, __ATOMIC_RELAXED, __HIP_MEMORY_SCOPE_AGENT);
      w1 = __hip_atomic_load(base + 1, __ATOMIC_RELAXED, __HIP_MEMORY_SCOPE_AGENT);
      w2 = __hip_atomic_load(base + 2, __ATOMIC_RELAXED, __HIP_MEMORY_SCOPE_AGENT);
      w3 = __hip_atomic_load(base + 3, __ATOMIC_RELAXED, __HIP_MEMORY_SCOPE_AGENT);
      if (((u32)(w0 >> 32) == (u32)SS) & ((u32)(w1 >> 32) == (u32)SS) &
          ((u32)(w2 >> 32) == (u32)SS) & ((u32)(w3 >> 32) == (u32)SS)) break;
      __builtin_amdgcn_s_sleep(1);
    } while (true);
    const int sp = d ? 0 : (SS - 1);
    *(float4*)&hist[(size_t)(sp * BB + bg * 2 + hc) * 512 + d * 256 + hk] =
        make_float4(__uint_as_float((u32)w0), __uint_as_float((u32)w1),
                    __uint_as_float((u32)w2), __uint_as_float((u32)w3));
  }
}

// ---------------- attention: scores over NS=16 sentence embs, softmax, g; writes comb[512:1024]
__global__ void att_kernel(float* __restrict__ comb, const float* __restrict__ sent) {
  __shared__ float sl[NSENT * 512];   // 32 KB
  __shared__ float wxr[512];
  __shared__ float parts[256];
  __shared__ float aw[NSENT];
  __shared__ float red0;
  const int tid = threadIdx.x;
  const int b = blockIdx.y;
  const int s0 = blockIdx.x * 32;
  for (int i = tid; i < NSENT * 512; i += 256) sl[i] = sent[(size_t)b * NSENT * 512 + i];
  __syncthreads();
  for (int si = 0; si < 32; ++si) {
    const int m = (s0 + si) * BB + b;
    float* crow = comb + (size_t)m * 1024;
    for (int i = tid; i < 512; i += 256) wxr[i] = crow[i];
    __syncthreads();
    const int n = tid >> 4, kp = tid & 15;
    float p = 0.f;
#pragma unroll 8
    for (int f = kp * 32; f < kp * 32 + 32; ++f) p = fmaf(wxr[f], sl[n * 512 + f], p);
    parts[tid] = p;
    __syncthreads();
    if (tid < NSENT) {
      float sc = 0.f;
      for (int qq = 0; qq < 16; ++qq) sc += parts[tid * 16 + qq];
      aw[tid] = sc;
    }
    __syncthreads();
    if (tid == 0) {
      float mx = aw[0];
      for (int qq = 1; qq < NSENT; ++qq) mx = fmaxf(mx, aw[qq]);
      float sm = 0.f;
      for (int qq = 0; qq < NSENT; ++qq) { float e = expf(aw[qq] - mx); aw[qq] = e; sm += e; }
      red0 = 1.f / sm;
    }
    __syncthreads();
    const float inv = red0;
    for (int f = tid; f < 512; f += 256) {
      float g = 0.f;
#pragma unroll
      for (int qq = 0; qq < NSENT; ++qq) g = fmaf(aw[qq], sl[qq * 512 + f], g);
      crow[512 + f] = g * inv;
    }
    __syncthreads();
  }
}

// ---------------- feats[m][t] = l2m[m][:] . h2t_w[t][:] + h2t_b[t]; wave per row
__global__ void feats_kernel(const float* __restrict__ l2m, const float* __restrict__ w,
                             const float* __restrict__ bias, float* __restrict__ feats) {
  const int wave = threadIdx.x >> 6, lane = threadIdx.x & 63;
  const int m = blockIdx.x * 4 + wave;
  const float* row = l2m + (size_t)m * 512;
  float rv[8];
#pragma unroll
  for (int i = 0; i < 8; ++i) rv[i] = row[lane + i * 64];
  for (int t = 0; t < TT; ++t) {
    const float* wr = w + t * 512;
    float p = 0.f;
#pragma unroll
    for (int i = 0; i < 8; ++i) p = fmaf(rv[i], wr[lane + i * 64], p);
#pragma unroll
    for (int off = 32; off; off >>= 1) p += __shfl_down(p, off);
    if (lane == 0) feats[(size_t)m * TT + t] = p + bias[t];
  }
}

// ---------------- viterbi per batch; 1 wave, whole DP in LDS
__global__ void viterbi_kernel(const float* __restrict__ feats, const float* __restrict__ trans,
                               int* __restrict__ out) {
  __shared__ float flds[SS * TT];
  __shared__ unsigned char bp[SS * TT];
  __shared__ float tr[TT * TT];
  __shared__ float fv[TT];
  __shared__ float tv[TT];
  __shared__ int pathS[SS];
  const int b = blockIdx.x, tid = threadIdx.x;
  for (int i = tid; i < SS * TT; i += 64) {
    int s = i / TT, t = i - s * TT;
    flds[i] = feats[(size_t)(s * BB + b) * TT + t];
  }
  for (int i = tid; i < TT * TT; i += 64) tr[i] = trans[i];
  if (tid < TT) fv[tid] = (tid == TAG_START) ? 0.f : -10000.f;
  __syncthreads();
  for (int s = 0; s < SS; ++s) {
    float nf = 0.f;
    if (tid < TT) {
      float mx = -1e30f;
      int bj = 0;
#pragma unroll
      for (int jj = 0; jj < TT; ++jj) {
        float v = fv[jj] + tr[tid * TT + jj];
        if (v > mx) { mx = v; bj = jj; }
      }
      nf = mx + flds[s * TT + tid];
      bp[s * TT + tid] = (unsigned char)bj;
    }
    __syncthreads();
    if (tid < TT) fv[tid] = nf;
    __syncthreads();
  }
  if (tid < TT) tv[tid] = fv[tid] + tr[TAG_STOP * TT + tid];
  __syncthreads();
  if (tid == 0) {
    int best = 0;
    float mx = tv[0];
    for (int jj = 1; jj < TT; ++jj)
      if (tv[jj] > mx) { mx = tv[jj]; best = jj; }
    pathS[SS - 1] = best;
    for (int s = SS - 1; s > 0; --s) { best = bp[s * TT + best]; pathS[s - 1] = best; }
  }
  __syncthreads();
  for (int s = tid; s < SS; s += 64) out[b * SS + s] = pathS[s];
}

// ---------------- workspace layout (bytes) — total ~240.4 MB < 256 MB ----------------
#define OFF_XP    ((size_t)0)               // 2*16384*1024*4 = 134217728
#define OFF_COMB  ((size_t)134217728)       // 16384*1024*4 = 67108864 (X1 and l2m alias here)
#define OFF_WORD  ((size_t)201326592)       // 16384*512*4  = 33554432
#define OFF_WT1   ((size_t)234881024)       // 2097152
#define OFF_WT2   ((size_t)236978176)       // 2097152
#define OFF_FEATS ((size_t)239075328)       // 786432
#define OFF_HX1   ((size_t)239861760)       // 262144  (2 slots * 2 dir * 16 g * 512 u64)
#define OFF_HX2   ((size_t)240123904)       // 262144

extern "C" void kernel_launch(void* const* d_in, const int* in_sizes, int n_in,
                              void* d_out, int out_size, void* d_ws, size_t ws_size,
                              hipStream_t stream) {
  const int* inputs  = (const int*)d_in[0];
  const float* sent  = (const float*)d_in[1];
  const float* emb   = (const float*)d_in[2];
  const float* l1wih = (const float*)d_in[3];
  const float* l1whh = (const float*)d_in[4];
  const float* l1b   = (const float*)d_in[5];
  const float* l2wih = (const float*)d_in[6];
  const float* l2whh = (const float*)d_in[7];
  const float* l2b   = (const float*)d_in[8];
  const float* attW  = (const float*)d_in[9];
  const float* h2tw  = (const float*)d_in[10];
  const float* h2tb  = (const float*)d_in[11];
  const float* trans = (const float*)d_in[12];
  int* out = (int*)d_out;
  char* ws = (char*)d_ws;

  float* Xp    = (float*)(ws + OFF_XP);
  float* comb  = (float*)(ws + OFF_COMB);
  float* word  = (float*)(ws + OFF_WORD);
  float* X1    = comb;   // X1 dead before comb is written (wx GEMM reads word only)
  float* l2m   = comb;   // comb dead before rec2 writes l2m
  float* wt1   = (float*)(ws + OFF_WT1);
  float* wt2   = (float*)(ws + OFF_WT2);
  float* feats = (float*)(ws + OFF_FEATS);
  u64* hx1     = (u64*)(ws + OFF_HX1);
  u64* hx2     = (u64*)(ws + OFF_HX2);

  // zero both tagged-h buffers (contiguous 512 KB): tag 0 == "h_{-1}=0 ready"
  hipMemsetAsync(ws + OFF_HX1, 0, 262144 * 2, stream);

  prep_whh<<<2048, 256, 0, stream>>>(l1whh, wt1);
  prep_whh<<<2048, 256, 0, stream>>>(l2whh, wt2);
  embed_kernel<<<MM, 64, 0, stream>>>(inputs, emb, X1);
  for (int d = 0; d < 2; ++d)
    gemm_nt<<<dim3(8, 128), 256, 0, stream>>>(X1, l1wih + (size_t)d * GG * DD,
                                              l1b + d * GG, Xp + (size_t)d * MM * GG,
                                              DD, GG);
  rec_kernel<<<256, 128, 0, stream>>>(Xp, wt1, word, hx1);
  gemm_nt<<<dim3(4, 128), 256, 0, stream>>>(word, attW, nullptr, comb, 512, 1024);
  att_kernel<<<dim3(16, 32), 256, 0, stream>>>(comb, sent);
  for (int d = 0; d < 2; ++d)
    gemm_nt<<<dim3(8, 128), 256, 0, stream>>>(comb, l2wih + (size_t)d * GG * GG,
                                              l2b + d * GG, Xp + (size_t)d * MM * GG,
                                              GG, GG);
  rec_kernel<<<256, 128, 0, stream>>>(Xp, wt2, l2m, hx2);
  feats_kernel<<<MM / 4, 256, 0, stream>>>(l2m, h2tw, h2tb, feats);
  viterbi_kernel<<<BB, 64, 0, stream>>>(feats, trans, out);
}

// Round 12
// 4895.321 us; speedup vs baseline: 1.1509x; 1.0345x over previous
//
#include <hip/hip_runtime.h>
#include <hip/hip_bf16.h>

// Problem constants
#define BB 32
#define SS 512
#define DD 256
#define HH 256
#define GG 1024          // 4*H
#define MM (SS*BB)       // 16384 rows, m = s*32 + b
#define NSENT 16
#define TT 12
#define TAG_START 10
#define TAG_STOP 11

typedef unsigned long long u64;
typedef unsigned int u32;

__device__ __forceinline__ float sigm(float x) {
  x = fminf(fmaxf(x, -15.f), 15.f);
  return 1.f / (1.f + __expf(-x));
}
__device__ __forceinline__ float tanh_fast(float x) {
  x = fminf(fmaxf(x, -15.f), 15.f);
  float e = __expf(2.f * x);
  return (e - 1.f) / (e + 1.f);
}

// ---------------- embed gather: X1[m][d] = embed[inputs[b][s]][d], m = s*32+b
__global__ void embed_kernel(const int* __restrict__ toks, const float* __restrict__ emb,
                             float* __restrict__ X1) {
  int m = blockIdx.x;
  int s = m >> 5, b = m & 31;
  int tok = toks[b * SS + s];
  ((float4*)(X1 + (size_t)m * DD))[threadIdx.x] =
      ((const float4*)(emb + (size_t)tok * DD))[threadIdx.x];
}

// ---------------- fp32 NT GEMM (R9-verified core, + lda/ldw strides):
// C[M,N] = A[M,K](lda) @ W[N,K](ldw)^T + bias.  128x128 tile, 8x8/thread.
__launch_bounds__(256)
__global__ void gemm_nt(const float* __restrict__ A, const float* __restrict__ W,
                        const float* __restrict__ bias, float* __restrict__ C,
                        int K, int lda, int ldw, int ldC) {
  __shared__ float As[16 * 132];
  __shared__ float Ws[16 * 132];
  const int tid = threadIdx.x;
  const int n0 = blockIdx.x * 128, m0 = blockIdx.y * 128;
  const int row = tid & 127, half = tid >> 7;    // staging: 128 rows x 2 k-halves
  const int tx = tid & 15, ty = tid >> 4;        // compute: 16x16 thread grid
  float acc[8][8] = {};
  const float* Arow = A + (size_t)(m0 + row) * lda;
  const float* Wrow = W + (size_t)(n0 + row) * ldw;
  for (int kk = 0; kk < K; kk += 16) {
    const int kb = half * 8;
    float4 a0 = *(const float4*)(Arow + kk + kb);
    float4 a1 = *(const float4*)(Arow + kk + kb + 4);
    float4 w0 = *(const float4*)(Wrow + kk + kb);
    float4 w1 = *(const float4*)(Wrow + kk + kb + 4);
    As[(kb + 0) * 132 + row] = a0.x; As[(kb + 1) * 132 + row] = a0.y;
    As[(kb + 2) * 132 + row] = a0.z; As[(kb + 3) * 132 + row] = a0.w;
    As[(kb + 4) * 132 + row] = a1.x; As[(kb + 5) * 132 + row] = a1.y;
    As[(kb + 6) * 132 + row] = a1.z; As[(kb + 7) * 132 + row] = a1.w;
    Ws[(kb + 0) * 132 + row] = w0.x; Ws[(kb + 1) * 132 + row] = w0.y;
    Ws[(kb + 2) * 132 + row] = w0.z; Ws[(kb + 3) * 132 + row] = w0.w;
    Ws[(kb + 4) * 132 + row] = w1.x; Ws[(kb + 5) * 132 + row] = w1.y;
    Ws[(kb + 6) * 132 + row] = w1.z; Ws[(kb + 7) * 132 + row] = w1.w;
    __syncthreads();
#pragma unroll
    for (int kl = 0; kl < 16; ++kl) {
      const float4 alo = *(const float4*)&As[kl * 132 + ty * 4];
      const float4 ahi = *(const float4*)&As[kl * 132 + 64 + ty * 4];
      const float4 wlo = *(const float4*)&Ws[kl * 132 + tx * 4];
      const float4 whi = *(const float4*)&Ws[kl * 132 + 64 + tx * 4];
      const float am[8] = {alo.x, alo.y, alo.z, alo.w, ahi.x, ahi.y, ahi.z, ahi.w};
      const float wm[8] = {wlo.x, wlo.y, wlo.z, wlo.w, whi.x, whi.y, whi.z, whi.w};
#pragma unroll
      for (int i = 0; i < 8; ++i)
#pragma unroll
        for (int j = 0; j < 8; ++j) acc[i][j] = fmaf(am[i], wm[j], acc[i][j]);
    }
    __syncthreads();
  }
  float4 blo = make_float4(0.f, 0.f, 0.f, 0.f), bhi = blo;
  if (bias) {
    blo = *(const float4*)(bias + n0 + tx * 4);
    bhi = *(const float4*)(bias + n0 + 64 + tx * 4);
  }
#pragma unroll
  for (int i = 0; i < 8; ++i) {
    const int m = m0 + ((i < 4) ? (ty * 4 + i) : (64 + ty * 4 + i - 4));
    float4 lo = make_float4(acc[i][0] + blo.x, acc[i][1] + blo.y,
                            acc[i][2] + blo.z, acc[i][3] + blo.w);
    float4 hi = make_float4(acc[i][4] + bhi.x, acc[i][5] + bhi.y,
                            acc[i][6] + bhi.z, acc[i][7] + bhi.w);
    *(float4*)(C + (size_t)m * ldC + n0 + tx * 4) = lo;
    *(float4*)(C + (size_t)m * ldC + n0 + 64 + tx * 4) = hi;
  }
}

// ---------------- whh repack (R6-verified): XOR-swizzle for conflict-free b128 reads.
__global__ void prep_whh(const float* __restrict__ whh, float* __restrict__ out) {
  int idx = blockIdx.x * 256 + threadIdx.x;        // 2*8*128*256 = 524288
  int pos = idx & 255;
  int r = (idx >> 8) & 127;
  int sl = (idx >> 15) & 7;
  int dir = idx >> 18;
  int ki = pos & 3;
  int k4 = (pos >> 2) ^ (r & 63);
  int k = k4 * 4 + ki;
  int g = (r >> 5) * 256 + sl * 32 + (r & 31);
  out[idx] = whh[(size_t)(dir * GG + g) * HH + k];
}

// ---------------- LSTM recurrence (R6/R11-verified core), one chain per wg.
// New: optional rank-16 attention-context add — xp += sum_n aw[m][n]*sentW[..][n][gcol],
// with sentW cached in registers at init and aw loads issued BEFORE the spin
// (hidden under the poll; occupancy is LDS-bound so the extra VGPRs are free).
__launch_bounds__(128)
__global__ void rec_kernel(const float* __restrict__ Xp, const float* __restrict__ whh_p,
                           float* __restrict__ hist, u64* __restrict__ hx,
                           const float* __restrict__ aw, const float* __restrict__ sentW,
                           int useAtt) {
  __shared__ float whh_lds[32768];   // [r*256 + swz(k)], 128KB
  __shared__ float h_lds[512];       // [c*256 + k]
  __shared__ float g_lds[256];       // [r*2 + c]
  const int tid = threadIdx.x;
  const int bid = blockIdx.x;
  const int sl = bid >> 5;
  const int db = bid & 31;
  const int d = db & 1;
  const int bg = db >> 1;
  const int r = tid;                 // gate row 0..127 (gate*32+j)
  const int swz = r & 63;
  const float* wp = whh_p + (size_t)(d * 8 + sl) * 32768;
  for (int i = tid * 4; i < 32768; i += 512)
    *(float4*)&whh_lds[i] = *(const float4*)&wp[i];
  const float* XpD = Xp + (size_t)d * MM * GG;
  const int gcol = (r >> 5) * 256 + sl * 32 + (r & 31);
  const int jj = tid & 31, cc = tid >> 5;        // producer epilogue mapping (tid<64)
  const int hc = tid >> 6, hk = (tid & 63) * 4;  // consumer word mapping: c*256+k = tid*4
  float creg = 0.f;                              // LSTM cell state (valid tid<64)
  // register-cached sentW columns for this thread's gate column (both batches)
  float sw0[16], sw1[16];
  if (useAtt) {
    const float* swp = sentW + ((size_t)d * 512 + (size_t)(bg * 2) * 16) * 1024 + gcol;
#pragma unroll
    for (int n = 0; n < 16; ++n) {
      sw0[n] = swp[(size_t)n * 1024];
      sw1[n] = swp[(size_t)(16 + n) * 1024];
    }
  }
  // group base: hx[slot][d][bg][512]
  u64* grp[2] = { hx + ((size_t)(0 * 2 + d) * 16 + bg) * 512,
                  hx + ((size_t)(1 * 2 + d) * 16 + bg) * 512 };
  __syncthreads();   // whh_lds ready
  for (int t = 0; t < SS; ++t) {
    const int s = d ? (SS - 1 - t) : t;
    // xp loads + rank-16 attention add issued before the spin (latency hidden)
    const int m0 = s * BB + bg * 2;
    float xp0 = XpD[(size_t)m0 * GG + gcol];
    float xp1 = XpD[(size_t)(m0 + 1) * GG + gcol];
    if (useAtt) {
      const float* a0 = aw + (size_t)m0 * 16;     // rows m0, m0+1 contiguous
#pragma unroll
      for (int n = 0; n < 16; ++n) {
        xp0 = fmaf(a0[n], sw0[n], xp0);
        xp1 = fmaf(a0[16 + n], sw1[n], xp1);
      }
    }
    // ---- per-thread barrier-free spin on my 4 tagged words ----
    u64 w0, w1, w2, w3;
    {
      u64* base = grp[t & 1] + tid * 4;
      w0 = __hip_atomic_load(base + 0, __ATOMIC_RELAXED, __HIP_MEMORY_SCOPE_AGENT);
      w1 = __hip_atomic_load(base + 1, __ATOMIC_RELAXED, __HIP_MEMORY_SCOPE_AGENT);
      w2 = __hip_atomic_load(base + 2, __ATOMIC_RELAXED, __HIP_MEMORY_SCOPE_AGENT);
      w3 = __hip_atomic_load(base + 3, __ATOMIC_RELAXED, __HIP_MEMORY_SCOPE_AGENT);
      while (((u32)(w0 >> 32) != (u32)t) | ((u32)(w1 >> 32) != (u32)t) |
             ((u32)(w2 >> 32) != (u32)t) | ((u32)(w3 >> 32) != (u32)t)) {
        __builtin_amdgcn_s_sleep(1);
        w0 = __hip_atomic_load(base + 0, __ATOMIC_RELAXED, __HIP_MEMORY_SCOPE_AGENT);
        w1 = __hip_atomic_load(base + 1, __ATOMIC_RELAXED, __HIP_MEMORY_SCOPE_AGENT);
        w2 = __hip_atomic_load(base + 2, __ATOMIC_RELAXED, __HIP_MEMORY_SCOPE_AGENT);
        w3 = __hip_atomic_load(base + 3, __ATOMIC_RELAXED, __HIP_MEMORY_SCOPE_AGENT);
      }
    }
    *(float4*)&h_lds[tid * 4] = make_float4(
        __uint_as_float((u32)w0), __uint_as_float((u32)w1),
        __uint_as_float((u32)w2), __uint_as_float((u32)w3));
    // consumer-side hist write for step t-1 (polled words = h_{t-1})
    if (sl == 0 && t > 0) {
      const int sp = d ? (SS - t) : (t - 1);
      *(float4*)&hist[(size_t)(sp * BB + bg * 2 + hc) * 512 + d * 256 + hk] =
          make_float4(__uint_as_float((u32)w0), __uint_as_float((u32)w1),
                      __uint_as_float((u32)w2), __uint_as_float((u32)w3));
    }
    __syncthreads();   // (b) h_lds complete
    {
      float acc0 = 0.f, acc1 = 0.f;
#pragma unroll 8
      for (int k4 = 0; k4 < 64; ++k4) {
        const float4 w = *(const float4*)&whh_lds[r * 256 + ((k4 ^ swz) << 2)];
        const float4 h0 = *(const float4*)&h_lds[k4 * 4];
        const float4 h1 = *(const float4*)&h_lds[256 + k4 * 4];
        acc0 = fmaf(w.x, h0.x, acc0); acc0 = fmaf(w.y, h0.y, acc0);
        acc0 = fmaf(w.z, h0.z, acc0); acc0 = fmaf(w.w, h0.w, acc0);
        acc1 = fmaf(w.x, h1.x, acc1); acc1 = fmaf(w.y, h1.y, acc1);
        acc1 = fmaf(w.z, h1.z, acc1); acc1 = fmaf(w.w, h1.w, acc1);
      }
      *(float2*)&g_lds[r * 2] = make_float2(acc0 + xp0, acc1 + xp1);
    }
    __syncthreads();   // (c) g_lds ready; also fences h_lds reads vs next-step writes
    if (tid < 64) {    // producer epilogue: single 8B L3 atomic on the critical path
      const float iv = g_lds[(jj) * 2 + cc];
      const float fv = g_lds[(32 + jj) * 2 + cc];
      const float gv = g_lds[(64 + jj) * 2 + cc];
      const float ov = g_lds[(96 + jj) * 2 + cc];
      const float cs = sigm(fv) * creg + sigm(iv) * tanh_fast(gv);
      creg = cs;
      const float hn = sigm(ov) * tanh_fast(cs);
      u64 w = ((u64)(u32)(t + 1) << 32) | (u64)__float_as_uint(hn);
      __hip_atomic_store(grp[(t + 1) & 1] + cc * 256 + sl * 32 + jj, w,
                         __ATOMIC_RELAXED, __HIP_MEMORY_SCOPE_AGENT);
    }
  }
  // flush the final h (tag SS) to hist — sl==0 wgs only
  if (sl == 0) {
    u64* base = grp[SS & 1] + tid * 4;
    u64 w0, w1, w2, w3;
    do {
      w0 = __hip_atomic_load(base + 0, __ATOMIC_RELAXED, __HIP_MEMORY_SCOPE_AGENT);
      w1 = __hip_atomic_load(base + 1, __ATOMIC_RELAXED, __HIP_MEMORY_SCOPE_AGENT);
      w2 = __hip_atomic_load(base + 2, __ATOMIC_RELAXED, __HIP_MEMORY_SCOPE_AGENT);
      w3 = __hip_atomic_load(base + 3, __ATOMIC_RELAXED, __HIP_MEMORY_SCOPE_AGENT);
      if (((u32)(w0 >> 32) == (u32)SS) & ((u32)(w1 >> 32) == (u32)SS) &
          ((u32)(w2 >> 32) == (u32)SS) & ((u32)(w3 >> 32) == (u32)SS)) break;
      __builtin_amdgcn_s_sleep(1);
    } while (true);
    const int sp = d ? 0 : (SS - 1);
    *(float4*)&hist[(size_t)(sp * BB + bg * 2 + hc) * 512 + d * 256 + hk] =
        make_float4(__uint_as_float((u32)w0), __uint_as_float((u32)w1),
                    __uint_as_float((u32)w2), __uint_as_float((u32)w3));
  }
}

// ---------------- aw: scores over NS=16 sentence embs + softmax -> aw[m][16]
// (g materialization eliminated — folded into rec2 via sentW)
__global__ void aw_kernel(const float* __restrict__ wx, const float* __restrict__ sent,
                          float* __restrict__ awout) {
  __shared__ float sl[NSENT * 512];   // 32 KB
  __shared__ float wxr[512];
  __shared__ float parts[256];
  __shared__ float avals[NSENT];
  __shared__ float red0;
  const int tid = threadIdx.x;
  const int b = blockIdx.y;
  const int s0 = blockIdx.x * 32;
  for (int i = tid; i < NSENT * 512; i += 256) sl[i] = sent[(size_t)b * NSENT * 512 + i];
  __syncthreads();
  for (int si = 0; si < 32; ++si) {
    const int m = (s0 + si) * BB + b;
    for (int i = tid; i < 512; i += 256) wxr[i] = wx[(size_t)m * 512 + i];
    __syncthreads();
    const int n = tid >> 4, kp = tid & 15;
    float p = 0.f;
#pragma unroll 8
    for (int f = kp * 32; f < kp * 32 + 32; ++f) p = fmaf(wxr[f], sl[n * 512 + f], p);
    parts[tid] = p;
    __syncthreads();
    if (tid < NSENT) {
      float sc = 0.f;
      for (int qq = 0; qq < 16; ++qq) sc += parts[tid * 16 + qq];
      avals[tid] = sc;
    }
    __syncthreads();
    if (tid == 0) {
      float mx = avals[0];
      for (int qq = 1; qq < NSENT; ++qq) mx = fmaxf(mx, avals[qq]);
      float sm = 0.f;
      for (int qq = 0; qq < NSENT; ++qq) { float e = expf(avals[qq] - mx); avals[qq] = e; sm += e; }
      red0 = 1.f / sm;
    }
    __syncthreads();
    if (tid < NSENT) awout[(size_t)m * 16 + tid] = avals[tid] * red0;
    __syncthreads();
  }
}

// ---------------- feats[m][t] = l2m[m][:] . h2t_w[t][:] + h2t_b[t]; wave per row
__global__ void feats_kernel(const float* __restrict__ l2m, const float* __restrict__ w,
                             const float* __restrict__ bias, float* __restrict__ feats) {
  const int wave = threadIdx.x >> 6, lane = threadIdx.x & 63;
  const int m = blockIdx.x * 4 + wave;
  const float* row = l2m + (size_t)m * 512;
  float rv[8];
#pragma unroll
  for (int i = 0; i < 8; ++i) rv[i] = row[lane + i * 64];
  for (int t = 0; t < TT; ++t) {
    const float* wr = w + t * 512;
    float p = 0.f;
#pragma unroll
    for (int i = 0; i < 8; ++i) p = fmaf(rv[i], wr[lane + i * 64], p);
#pragma unroll
    for (int off = 32; off; off >>= 1) p += __shfl_down(p, off);
    if (lane == 0) feats[(size_t)m * TT + t] = p + bias[t];
  }
}

// ---------------- viterbi per batch; 1 wave, whole DP in LDS
__global__ void viterbi_kernel(const float* __restrict__ feats, const float* __restrict__ trans,
                               int* __restrict__ out) {
  __shared__ float flds[SS * TT];
  __shared__ unsigned char bp[SS * TT];
  __shared__ float tr[TT * TT];
  __shared__ float fv[TT];
  __shared__ float tv[TT];
  __shared__ int pathS[SS];
  const int b = blockIdx.x, tid = threadIdx.x;
  for (int i = tid; i < SS * TT; i += 64) {
    int s = i / TT, t = i - s * TT;
    flds[i] = feats[(size_t)(s * BB + b) * TT + t];
  }
  for (int i = tid; i < TT * TT; i += 64) tr[i] = trans[i];
  if (tid < TT) fv[tid] = (tid == TAG_START) ? 0.f : -10000.f;
  __syncthreads();
  for (int s = 0; s < SS; ++s) {
    float nf = 0.f;
    if (tid < TT) {
      float mx = -1e30f;
      int bj = 0;
#pragma unroll
      for (int jj = 0; jj < TT; ++jj) {
        float v = fv[jj] + tr[tid * TT + jj];
        if (v > mx) { mx = v; bj = jj; }
      }
      nf = mx + flds[s * TT + tid];
      bp[s * TT + tid] = (unsigned char)bj;
    }
    __syncthreads();
    if (tid < TT) fv[tid] = nf;
    __syncthreads();
  }
  if (tid < TT) tv[tid] = fv[tid] + tr[TAG_STOP * TT + tid];
  __syncthreads();
  if (tid == 0) {
    int best = 0;
    float mx = tv[0];
    for (int jj = 1; jj < TT; ++jj)
      if (tv[jj] > mx) { mx = tv[jj]; best = jj; }
    pathS[SS - 1] = best;
    for (int s = SS - 1; s > 0; --s) { best = bp[s * TT + best]; pathS[s - 1] = best; }
  }
  __syncthreads();
  for (int s = tid; s < SS; s += 64) out[b * SS + s] = pathS[s];
}

// ---------------- workspace layout (bytes) — total ~245.6 MB < 256 MB ----------------
#define OFF_XP    ((size_t)0)               // 2*16384*1024*4 = 134217728
#define OFF_WX    ((size_t)134217728)       // 16384*512*4 = 33554432
#define OFF_L2M   ((size_t)167772160)       // 16384*512*4 = 33554432 (X1 aliases here)
#define OFF_WORD  ((size_t)201326592)       // 16384*512*4 = 33554432
#define OFF_WT1   ((size_t)234881024)       // 2097152
#define OFF_WT2   ((size_t)236978176)       // 2097152
#define OFF_FEATS ((size_t)239075328)       // 786432
#define OFF_HX1   ((size_t)239861760)       // 262144
#define OFF_HX2   ((size_t)240123904)       // 262144
#define OFF_SENTW ((size_t)240386048)       // 2*512*1024*4 = 4194304
#define OFF_AW    ((size_t)244580352)       // 16384*16*4 = 1048576

extern "C" void kernel_launch(void* const* d_in, const int* in_sizes, int n_in,
                              void* d_out, int out_size, void* d_ws, size_t ws_size,
                              hipStream_t stream) {
  const int* inputs  = (const int*)d_in[0];
  const float* sent  = (const float*)d_in[1];
  const float* emb   = (const float*)d_in[2];
  const float* l1wih = (const float*)d_in[3];
  const float* l1whh = (const float*)d_in[4];
  const float* l1b   = (const float*)d_in[5];
  const float* l2wih = (const float*)d_in[6];
  const float* l2whh = (const float*)d_in[7];
  const float* l2b   = (const float*)d_in[8];
  const float* attW  = (const float*)d_in[9];
  const float* h2tw  = (const float*)d_in[10];
  const float* h2tb  = (const float*)d_in[11];
  const float* trans = (const float*)d_in[12];
  int* out = (int*)d_out;
  char* ws = (char*)d_ws;

  float* Xp    = (float*)(ws + OFF_XP);
  float* wx    = (float*)(ws + OFF_WX);
  float* l2m   = (float*)(ws + OFF_L2M);
  float* X1    = l2m;    // X1 dead (read only by l1 gemms) before rec2 writes l2m
  float* word  = (float*)(ws + OFF_WORD);
  float* wt1   = (float*)(ws + OFF_WT1);
  float* wt2   = (float*)(ws + OFF_WT2);
  float* feats = (float*)(ws + OFF_FEATS);
  u64* hx1     = (u64*)(ws + OFF_HX1);
  u64* hx2     = (u64*)(ws + OFF_HX2);
  float* sentW = (float*)(ws + OFF_SENTW);
  float* awb   = (float*)(ws + OFF_AW);

  // zero both tagged-h buffers (contiguous 512 KB): tag 0 == "h_{-1}=0 ready"
  hipMemsetAsync(ws + OFF_HX1, 0, 262144 * 2, stream);

  prep_whh<<<2048, 256, 0, stream>>>(l1whh, wt1);
  prep_whh<<<2048, 256, 0, stream>>>(l2whh, wt2);
  // sentW[d][b*16+n][g] = sent[b][n][:512] . l2wih[d][g][512:1024]
  for (int d = 0; d < 2; ++d)
    gemm_nt<<<dim3(8, 4), 256, 0, stream>>>(sent, l2wih + (size_t)d * GG * GG + 512,
                                            nullptr, sentW + (size_t)d * 512 * 1024,
                                            512, 512, GG, 1024);
  embed_kernel<<<MM, 64, 0, stream>>>(inputs, emb, X1);
  for (int d = 0; d < 2; ++d)
    gemm_nt<<<dim3(8, 128), 256, 0, stream>>>(X1, l1wih + (size_t)d * GG * DD,
                                              l1b + d * GG, Xp + (size_t)d * MM * GG,
                                              DD, DD, DD, GG);
  rec_kernel<<<256, 128, 0, stream>>>(Xp, wt1, word, hx1, nullptr, nullptr, 0);
  // wx = word @ attW^T
  gemm_nt<<<dim3(4, 128), 256, 0, stream>>>(word, attW, nullptr, wx, 512, 512, 512, 512);
  aw_kernel<<<dim3(16, 32), 256, 0, stream>>>(wx, sent, awb);
  // Xp2 = wx @ l2wih[:, :512]^T + bias   (K halved; attention half folded into rec2)
  for (int d = 0; d < 2; ++d)
    gemm_nt<<<dim3(8, 128), 256, 0, stream>>>(wx, l2wih + (size_t)d * GG * GG,
                                              l2b + d * GG, Xp + (size_t)d * MM * GG,
                                              512, 512, GG, GG);
  rec_kernel<<<256, 128, 0, stream>>>(Xp, wt2, l2m, hx2, awb, sentW, 1);
  feats_kernel<<<MM / 4, 256, 0, stream>>>(l2m, h2tw, h2tb, feats);
  viterbi_kernel<<<BB, 64, 0, stream>>>(feats, trans, out);
}

// Round 13
// 4632.472 us; speedup vs baseline: 1.2162x; 1.0567x over previous
//
#include <hip/hip_runtime.h>
#include <hip/hip_bf16.h>

// Problem constants
#define BB 32
#define SS 512
#define DD 256
#define HH 256
#define GG 1024          // 4*H
#define MM (SS*BB)       // 16384 rows, m = s*32 + b
#define NSENT 16
#define TT 12
#define TAG_START 10
#define TAG_STOP 11

typedef unsigned long long u64;
typedef unsigned int u32;

__device__ __forceinline__ float sigm(float x) {
  x = fminf(fmaxf(x, -15.f), 15.f);
  return 1.f / (1.f + __expf(-x));
}
__device__ __forceinline__ float tanh_fast(float x) {
  x = fminf(fmaxf(x, -15.f), 15.f);
  float e = __expf(2.f * x);
  return (e - 1.f) / (e + 1.f);
}

// ---------------- embed gather: X1[m][d] = embed[inputs[b][s]][d], m = s*32+b
__global__ void embed_kernel(const int* __restrict__ toks, const float* __restrict__ emb,
                             float* __restrict__ X1) {
  int m = blockIdx.x;
  int s = m >> 5, b = m & 31;
  int tok = toks[b * SS + s];
  ((float4*)(X1 + (size_t)m * DD))[threadIdx.x] =
      ((const float4*)(emb + (size_t)tok * DD))[threadIdx.x];
}

// ---------------- fp32 NT GEMM (R9-verified core + z-batching):
// C[M,N] = A[M,K](lda) @ W[N,K](ldw)^T + bias.  128x128 tile, 8x8/thread.
// blockIdx.z selects direction: W += z*wz, C += z*cz, bias += z*GG.
__launch_bounds__(256)
__global__ void gemm_nt(const float* __restrict__ A, const float* __restrict__ W_,
                        const float* __restrict__ bias_, float* __restrict__ C_,
                        int K, int lda, int ldw, int ldC, size_t wz, size_t cz) {
  __shared__ float As[16 * 132];
  __shared__ float Ws[16 * 132];
  const float* W = W_ + (size_t)blockIdx.z * wz;
  const float* bias = bias_ ? bias_ + (size_t)blockIdx.z * GG : nullptr;
  float* C = C_ + (size_t)blockIdx.z * cz;
  const int tid = threadIdx.x;
  const int n0 = blockIdx.x * 128, m0 = blockIdx.y * 128;
  const int row = tid & 127, half = tid >> 7;    // staging: 128 rows x 2 k-halves
  const int tx = tid & 15, ty = tid >> 4;        // compute: 16x16 thread grid
  float acc[8][8] = {};
  const float* Arow = A + (size_t)(m0 + row) * lda;
  const float* Wrow = W + (size_t)(n0 + row) * ldw;
  for (int kk = 0; kk < K; kk += 16) {
    const int kb = half * 8;
    float4 a0 = *(const float4*)(Arow + kk + kb);
    float4 a1 = *(const float4*)(Arow + kk + kb + 4);
    float4 w0 = *(const float4*)(Wrow + kk + kb);
    float4 w1 = *(const float4*)(Wrow + kk + kb + 4);
    As[(kb + 0) * 132 + row] = a0.x; As[(kb + 1) * 132 + row] = a0.y;
    As[(kb + 2) * 132 + row] = a0.z; As[(kb + 3) * 132 + row] = a0.w;
    As[(kb + 4) * 132 + row] = a1.x; As[(kb + 5) * 132 + row] = a1.y;
    As[(kb + 6) * 132 + row] = a1.z; As[(kb + 7) * 132 + row] = a1.w;
    Ws[(kb + 0) * 132 + row] = w0.x; Ws[(kb + 1) * 132 + row] = w0.y;
    Ws[(kb + 2) * 132 + row] = w0.z; Ws[(kb + 3) * 132 + row] = w0.w;
    Ws[(kb + 4) * 132 + row] = w1.x; Ws[(kb + 5) * 132 + row] = w1.y;
    Ws[(kb + 6) * 132 + row] = w1.z; Ws[(kb + 7) * 132 + row] = w1.w;
    __syncthreads();
#pragma unroll
    for (int kl = 0; kl < 16; ++kl) {
      const float4 alo = *(const float4*)&As[kl * 132 + ty * 4];
      const float4 ahi = *(const float4*)&As[kl * 132 + 64 + ty * 4];
      const float4 wlo = *(const float4*)&Ws[kl * 132 + tx * 4];
      const float4 whi = *(const float4*)&Ws[kl * 132 + 64 + tx * 4];
      const float am[8] = {alo.x, alo.y, alo.z, alo.w, ahi.x, ahi.y, ahi.z, ahi.w};
      const float wm[8] = {wlo.x, wlo.y, wlo.z, wlo.w, whi.x, whi.y, whi.z, whi.w};
#pragma unroll
      for (int i = 0; i < 8; ++i)
#pragma unroll
        for (int j = 0; j < 8; ++j) acc[i][j] = fmaf(am[i], wm[j], acc[i][j]);
    }
    __syncthreads();
  }
  float4 blo = make_float4(0.f, 0.f, 0.f, 0.f), bhi = blo;
  if (bias) {
    blo = *(const float4*)(bias + n0 + tx * 4);
    bhi = *(const float4*)(bias + n0 + 64 + tx * 4);
  }
#pragma unroll
  for (int i = 0; i < 8; ++i) {
    const int m = m0 + ((i < 4) ? (ty * 4 + i) : (64 + ty * 4 + i - 4));
    float4 lo = make_float4(acc[i][0] + blo.x, acc[i][1] + blo.y,
                            acc[i][2] + blo.z, acc[i][3] + blo.w);
    float4 hi = make_float4(acc[i][4] + bhi.x, acc[i][5] + bhi.y,
                            acc[i][6] + bhi.z, acc[i][7] + bhi.w);
    *(float4*)(C + (size_t)m * ldC + n0 + tx * 4) = lo;
    *(float4*)(C + (size_t)m * ldC + n0 + 64 + tx * 4) = hi;
  }
}

// ---------------- whh repack (R6-verified), both layers in one launch.
__global__ void prep_whh(const float* __restrict__ whh1, const float* __restrict__ whh2,
                         float* __restrict__ o1, float* __restrict__ o2) {
  int idx0 = blockIdx.x * 256 + threadIdx.x;       // 2 * 524288
  int layer = idx0 >> 19;
  int idx = idx0 & 524287;
  const float* whh = layer ? whh2 : whh1;
  float* out = layer ? o2 : o1;
  int pos = idx & 255;
  int r = (idx >> 8) & 127;
  int sl = (idx >> 15) & 7;
  int dir = idx >> 18;
  int ki = pos & 3;
  int k4 = (pos >> 2) ^ (r & 63);
  int k = k4 * 4 + ki;
  int g = (r >> 5) * 256 + sl * 32 + (r & 31);
  out[idx] = whh[(size_t)(dir * GG + g) * HH + k];
}

// ---------------- LSTM recurrence (R6/R11/R12-verified core), one chain per wg.
// hist writes are DISTRIBUTED: the 16 threads whose polled words hold the wg's
// own slice columns ((tid&63)>>3 == sl) write them — every wg does identical
// tiny work, removing the sl==0 per-step skew tax on the sync group.
__launch_bounds__(128)
__global__ void rec_kernel(const float* __restrict__ Xp, const float* __restrict__ whh_p,
                           float* __restrict__ hist, u64* __restrict__ hx,
                           const float* __restrict__ aw, const float* __restrict__ sentW,
                           int useAtt) {
  __shared__ float whh_lds[32768];   // [r*256 + swz(k)], 128KB
  __shared__ float h_lds[512];       // [c*256 + k]
  __shared__ float g_lds[256];       // [r*2 + c]
  const int tid = threadIdx.x;
  const int bid = blockIdx.x;
  const int sl = bid >> 5;
  const int db = bid & 31;
  const int d = db & 1;
  const int bg = db >> 1;
  const int r = tid;                 // gate row 0..127 (gate*32+j)
  const int swz = r & 63;
  const float* wp = whh_p + (size_t)(d * 8 + sl) * 32768;
  for (int i = tid * 4; i < 32768; i += 512)
    *(float4*)&whh_lds[i] = *(const float4*)&wp[i];
  const float* XpD = Xp + (size_t)d * MM * GG;
  const int gcol = (r >> 5) * 256 + sl * 32 + (r & 31);
  const int jj = tid & 31, cc = tid >> 5;        // producer epilogue mapping (tid<64)
  const int hc = tid >> 6, hk = (tid & 63) * 4;  // polled-word mapping: c*256+k = tid*4
  const int histMine = (((tid & 63) >> 3) == sl);// my words = my wg's hist slice
  float creg = 0.f;                              // LSTM cell state (valid tid<64)
  // register-cached sentW columns for this thread's gate column (both batches)
  float sw0[16], sw1[16];
  if (useAtt) {
    const float* swp = sentW + ((size_t)d * 512 + (size_t)(bg * 2) * 16) * 1024 + gcol;
#pragma unroll
    for (int n = 0; n < 16; ++n) {
      sw0[n] = swp[(size_t)n * 1024];
      sw1[n] = swp[(size_t)(16 + n) * 1024];
    }
  }
  // group base: hx[slot][d][bg][512]
  u64* grp[2] = { hx + ((size_t)(0 * 2 + d) * 16 + bg) * 512,
                  hx + ((size_t)(1 * 2 + d) * 16 + bg) * 512 };
  __syncthreads();   // whh_lds ready
  for (int t = 0; t < SS; ++t) {
    const int s = d ? (SS - 1 - t) : t;
    // xp loads + rank-16 attention add issued before the spin (latency hidden)
    const int m0 = s * BB + bg * 2;
    float xp0 = XpD[(size_t)m0 * GG + gcol];
    float xp1 = XpD[(size_t)(m0 + 1) * GG + gcol];
    if (useAtt) {
      const float* a0 = aw + (size_t)m0 * 16;     // rows m0, m0+1 contiguous
#pragma unroll
      for (int n = 0; n < 16; ++n) {
        xp0 = fmaf(a0[n], sw0[n], xp0);
        xp1 = fmaf(a0[16 + n], sw1[n], xp1);
      }
    }
    // ---- per-thread barrier-free spin on my 4 tagged words ----
    u64 w0, w1, w2, w3;
    {
      u64* base = grp[t & 1] + tid * 4;
      w0 = __hip_atomic_load(base + 0, __ATOMIC_RELAXED, __HIP_MEMORY_SCOPE_AGENT);
      w1 = __hip_atomic_load(base + 1, __ATOMIC_RELAXED, __HIP_MEMORY_SCOPE_AGENT);
      w2 = __hip_atomic_load(base + 2, __ATOMIC_RELAXED, __HIP_MEMORY_SCOPE_AGENT);
      w3 = __hip_atomic_load(base + 3, __ATOMIC_RELAXED, __HIP_MEMORY_SCOPE_AGENT);
      while (((u32)(w0 >> 32) != (u32)t) | ((u32)(w1 >> 32) != (u32)t) |
             ((u32)(w2 >> 32) != (u32)t) | ((u32)(w3 >> 32) != (u32)t)) {
        __builtin_amdgcn_s_sleep(1);
        w0 = __hip_atomic_load(base + 0, __ATOMIC_RELAXED, __HIP_MEMORY_SCOPE_AGENT);
        w1 = __hip_atomic_load(base + 1, __ATOMIC_RELAXED, __HIP_MEMORY_SCOPE_AGENT);
        w2 = __hip_atomic_load(base + 2, __ATOMIC_RELAXED, __HIP_MEMORY_SCOPE_AGENT);
        w3 = __hip_atomic_load(base + 3, __ATOMIC_RELAXED, __HIP_MEMORY_SCOPE_AGENT);
      }
    }
    *(float4*)&h_lds[tid * 4] = make_float4(
        __uint_as_float((u32)w0), __uint_as_float((u32)w1),
        __uint_as_float((u32)w2), __uint_as_float((u32)w3));
    // distributed hist write for step t-1 (polled words = h_{t-1})
    if (histMine && t > 0) {
      const int sp = d ? (SS - t) : (t - 1);
      *(float4*)&hist[(size_t)(sp * BB + bg * 2 + hc) * 512 + d * 256 + hk] =
          make_float4(__uint_as_float((u32)w0), __uint_as_float((u32)w1),
                      __uint_as_float((u32)w2), __uint_as_float((u32)w3));
    }
    __syncthreads();   // (b) h_lds complete
    {
      float acc0 = 0.f, acc1 = 0.f;
#pragma unroll 8
      for (int k4 = 0; k4 < 64; ++k4) {
        const float4 w = *(const float4*)&whh_lds[r * 256 + ((k4 ^ swz) << 2)];
        const float4 h0 = *(const float4*)&h_lds[k4 * 4];
        const float4 h1 = *(const float4*)&h_lds[256 + k4 * 4];
        acc0 = fmaf(w.x, h0.x, acc0); acc0 = fmaf(w.y, h0.y, acc0);
        acc0 = fmaf(w.z, h0.z, acc0); acc0 = fmaf(w.w, h0.w, acc0);
        acc1 = fmaf(w.x, h1.x, acc1); acc1 = fmaf(w.y, h1.y, acc1);
        acc1 = fmaf(w.z, h1.z, acc1); acc1 = fmaf(w.w, h1.w, acc1);
      }
      *(float2*)&g_lds[r * 2] = make_float2(acc0 + xp0, acc1 + xp1);
    }
    __syncthreads();   // (c) g_lds ready; also fences h_lds reads vs next-step writes
    if (tid < 64) {    // producer epilogue: single 8B L3 atomic on the critical path
      const float iv = g_lds[(jj) * 2 + cc];
      const float fv = g_lds[(32 + jj) * 2 + cc];
      const float gv = g_lds[(64 + jj) * 2 + cc];
      const float ov = g_lds[(96 + jj) * 2 + cc];
      const float cs = sigm(fv) * creg + sigm(iv) * tanh_fast(gv);
      creg = cs;
      const float hn = sigm(ov) * tanh_fast(cs);
      u64 w = ((u64)(u32)(t + 1) << 32) | (u64)__float_as_uint(hn);
      __hip_atomic_store(grp[(t + 1) & 1] + cc * 256 + sl * 32 + jj, w,
                         __ATOMIC_RELAXED, __HIP_MEMORY_SCOPE_AGENT);
    }
  }
  // distributed final flush (tag SS): each participating thread polls its OWN words
  if (histMine) {
    u64* base = grp[SS & 1] + tid * 4;
    u64 w0, w1, w2, w3;
    do {
      w0 = __hip_atomic_load(base + 0, __ATOMIC_RELAXED, __HIP_MEMORY_SCOPE_AGENT);
      w1 = __hip_atomic_load(base + 1, __ATOMIC_RELAXED, __HIP_MEMORY_SCOPE_AGENT);
      w2 = __hip_atomic_load(base + 2, __ATOMIC_RELAXED, __HIP_MEMORY_SCOPE_AGENT);
      w3 = __hip_atomic_load(base + 3, __ATOMIC_RELAXED, __HIP_MEMORY_SCOPE_AGENT);
      if (((u32)(w0 >> 32) == (u32)SS) & ((u32)(w1 >> 32) == (u32)SS) &
          ((u32)(w2 >> 32) == (u32)SS) & ((u32)(w3 >> 32) == (u32)SS)) break;
      __builtin_amdgcn_s_sleep(1);
    } while (true);
    const int sp = d ? 0 : (SS - 1);
    *(float4*)&hist[(size_t)(sp * BB + bg * 2 + hc) * 512 + d * 256 + hk] =
        make_float4(__uint_as_float((u32)w0), __uint_as_float((u32)w1),
                    __uint_as_float((u32)w2), __uint_as_float((u32)w3));
  }
}

// ---------------- aw: scores over NS=16 sentence embs + softmax -> aw[m][16]
__global__ void aw_kernel(const float* __restrict__ wx, const float* __restrict__ sent,
                          float* __restrict__ awout) {
  __shared__ float sl[NSENT * 512];   // 32 KB
  __shared__ float wxr[512];
  __shared__ float parts[256];
  __shared__ float avals[NSENT];
  __shared__ float red0;
  const int tid = threadIdx.x;
  const int b = blockIdx.y;
  const int s0 = blockIdx.x * 32;
  for (int i = tid; i < NSENT * 512; i += 256) sl[i] = sent[(size_t)b * NSENT * 512 + i];
  __syncthreads();
  for (int si = 0; si < 32; ++si) {
    const int m = (s0 + si) * BB + b;
    for (int i = tid; i < 512; i += 256) wxr[i] = wx[(size_t)m * 512 + i];
    __syncthreads();
    const int n = tid >> 4, kp = tid & 15;
    float p = 0.f;
#pragma unroll 8
    for (int f = kp * 32; f < kp * 32 + 32; ++f) p = fmaf(wxr[f], sl[n * 512 + f], p);
    parts[tid] = p;
    __syncthreads();
    if (tid < NSENT) {
      float sc = 0.f;
      for (int qq = 0; qq < 16; ++qq) sc += parts[tid * 16 + qq];
      avals[tid] = sc;
    }
    __syncthreads();
    if (tid == 0) {
      float mx = avals[0];
      for (int qq = 1; qq < NSENT; ++qq) mx = fmaxf(mx, avals[qq]);
      float sm = 0.f;
      for (int qq = 0; qq < NSENT; ++qq) { float e = expf(avals[qq] - mx); avals[qq] = e; sm += e; }
      red0 = 1.f / sm;
    }
    __syncthreads();
    if (tid < NSENT) awout[(size_t)m * 16 + tid] = avals[tid] * red0;
    __syncthreads();
  }
}

// ---------------- feats[m][t] = l2m[m][:] . h2t_w[t][:] + h2t_b[t]; wave per row
__global__ void feats_kernel(const float* __restrict__ l2m, const float* __restrict__ w,
                             const float* __restrict__ bias, float* __restrict__ feats) {
  const int wave = threadIdx.x >> 6, lane = threadIdx.x & 63;
  const int m = blockIdx.x * 4 + wave;
  const float* row = l2m + (size_t)m * 512;
  float rv[8];
#pragma unroll
  for (int i = 0; i < 8; ++i) rv[i] = row[lane + i * 64];
  for (int t = 0; t < TT; ++t) {
    const float* wr = w + t * 512;
    float p = 0.f;
#pragma unroll
    for (int i = 0; i < 8; ++i) p = fmaf(rv[i], wr[lane + i * 64], p);
#pragma unroll
    for (int off = 32; off; off >>= 1) p += __shfl_down(p, off);
    if (lane == 0) feats[(size_t)m * TT + t] = p + bias[t];
  }
}

// ---------------- viterbi per batch; 1 wave, whole DP in LDS
__global__ void viterbi_kernel(const float* __restrict__ feats, const float* __restrict__ trans,
                               int* __restrict__ out) {
  __shared__ float flds[SS * TT];
  __shared__ unsigned char bp[SS * TT];
  __shared__ float tr[TT * TT];
  __shared__ float fv[TT];
  __shared__ float tv[TT];
  __shared__ int pathS[SS];
  const int b = blockIdx.x, tid = threadIdx.x;
  for (int i = tid; i < SS * TT; i += 64) {
    int s = i / TT, t = i - s * TT;
    flds[i] = feats[(size_t)(s * BB + b) * TT + t];
  }
  for (int i = tid; i < TT * TT; i += 64) tr[i] = trans[i];
  if (tid < TT) fv[tid] = (tid == TAG_START) ? 0.f : -10000.f;
  __syncthreads();
  for (int s = 0; s < SS; ++s) {
    float nf = 0.f;
    if (tid < TT) {
      float mx = -1e30f;
      int bj = 0;
#pragma unroll
      for (int jj = 0; jj < TT; ++jj) {
        float v = fv[jj] + tr[tid * TT + jj];
        if (v > mx) { mx = v; bj = jj; }
      }
      nf = mx + flds[s * TT + tid];
      bp[s * TT + tid] = (unsigned char)bj;
    }
    __syncthreads();
    if (tid < TT) fv[tid] = nf;
    __syncthreads();
  }
  if (tid < TT) tv[tid] = fv[tid] + tr[TAG_STOP * TT + tid];
  __syncthreads();
  if (tid == 0) {
    int best = 0;
    float mx = tv[0];
    for (int jj = 1; jj < TT; ++jj)
      if (tv[jj] > mx) { mx = tv[jj]; best = jj; }
    pathS[SS - 1] = best;
    for (int s = SS - 1; s > 0; --s) { best = bp[s * TT + best]; pathS[s - 1] = best; }
  }
  __syncthreads();
  for (int s = tid; s < SS; s += 64) out[b * SS + s] = pathS[s];
}

// ---------------- workspace layout (bytes) — total ~245.6 MB < 256 MB ----------------
#define OFF_XP    ((size_t)0)               // 2*16384*1024*4 = 134217728
#define OFF_WX    ((size_t)134217728)       // 16384*512*4 = 33554432
#define OFF_L2M   ((size_t)167772160)       // 16384*512*4 = 33554432 (X1 aliases here)
#define OFF_WORD  ((size_t)201326592)       // 16384*512*4 = 33554432
#define OFF_WT1   ((size_t)234881024)       // 2097152
#define OFF_WT2   ((size_t)236978176)       // 2097152
#define OFF_FEATS ((size_t)239075328)       // 786432
#define OFF_HX1   ((size_t)239861760)       // 262144
#define OFF_HX2   ((size_t)240123904)       // 262144
#define OFF_SENTW ((size_t)240386048)       // 2*512*1024*4 = 4194304
#define OFF_AW    ((size_t)244580352)       // 16384*16*4 = 1048576

extern "C" void kernel_launch(void* const* d_in, const int* in_sizes, int n_in,
                              void* d_out, int out_size, void* d_ws, size_t ws_size,
                              hipStream_t stream) {
  const int* inputs  = (const int*)d_in[0];
  const float* sent  = (const float*)d_in[1];
  const float* emb   = (const float*)d_in[2];
  const float* l1wih = (const float*)d_in[3];
  const float* l1whh = (const float*)d_in[4];
  const float* l1b   = (const float*)d_in[5];
  const float* l2wih = (const float*)d_in[6];
  const float* l2whh = (const float*)d_in[7];
  const float* l2b   = (const float*)d_in[8];
  const float* attW  = (const float*)d_in[9];
  const float* h2tw  = (const float*)d_in[10];
  const float* h2tb  = (const float*)d_in[11];
  const float* trans = (const float*)d_in[12];
  int* out = (int*)d_out;
  char* ws = (char*)d_ws;

  float* Xp    = (float*)(ws + OFF_XP);
  float* wx    = (float*)(ws + OFF_WX);
  float* l2m   = (float*)(ws + OFF_L2M);
  float* X1    = l2m;    // X1 dead (read only by l1 gemms) before rec2 writes l2m
  float* word  = (float*)(ws + OFF_WORD);
  float* wt1   = (float*)(ws + OFF_WT1);
  float* wt2   = (float*)(ws + OFF_WT2);
  float* feats = (float*)(ws + OFF_FEATS);
  u64* hx1     = (u64*)(ws + OFF_HX1);
  u64* hx2     = (u64*)(ws + OFF_HX2);
  float* sentW = (float*)(ws + OFF_SENTW);
  float* awb   = (float*)(ws + OFF_AW);

  // zero both tagged-h buffers (contiguous 512 KB): tag 0 == "h_{-1}=0 ready"
  hipMemsetAsync(ws + OFF_HX1, 0, 262144 * 2, stream);

  prep_whh<<<4096, 256, 0, stream>>>(l1whh, l2whh, wt1, wt2);
  // sentW[d][b*16+n][g] = sent[b][n][:512] . l2wih[d][g][512:1024]
  gemm_nt<<<dim3(8, 4, 2), 256, 0, stream>>>(sent, l2wih + 512, nullptr, sentW,
                                             512, 512, GG, 1024,
                                             (size_t)GG * GG, (size_t)512 * 1024);
  embed_kernel<<<MM, 64, 0, stream>>>(inputs, emb, X1);
  gemm_nt<<<dim3(8, 128, 2), 256, 0, stream>>>(X1, l1wih, l1b, Xp,
                                               DD, DD, DD, GG,
                                               (size_t)GG * DD, (size_t)MM * GG);
  rec_kernel<<<256, 128, 0, stream>>>(Xp, wt1, word, hx1, nullptr, nullptr, 0);
  // wx = word @ attW^T
  gemm_nt<<<dim3(4, 128, 1), 256, 0, stream>>>(word, attW, nullptr, wx,
                                               512, 512, 512, 512, 0, 0);
  aw_kernel<<<dim3(16, 32), 256, 0, stream>>>(wx, sent, awb);
  // Xp2 = wx @ l2wih[:, :512]^T + bias   (K halved; attention half folded into rec2)
  gemm_nt<<<dim3(8, 128, 2), 256, 0, stream>>>(wx, l2wih, l2b, Xp,
                                               512, 512, GG, GG,
                                               (size_t)GG * GG, (size_t)MM * GG);
  rec_kernel<<<256, 128, 0, stream>>>(Xp, wt2, l2m, hx2, awb, sentW, 1);
  feats_kernel<<<MM / 4, 256, 0, stream>>>(l2m, h2tw, h2tb, feats);
  viterbi_kernel<<<BB, 64, 0, stream>>>(feats, trans, out);
}